// Round 1
// baseline (1247.919 us; speedup 1.0000x reference)
//
#include <hip/hip_runtime.h>

// Problem constants (fixed-shape problem)
#define NV 20000
#define NE 240000
#define PER 5000
#define DEG 16
#define EPB 80000            // edges per level block
#define SCALE 0.07216878364870323f   // (3*64)^-0.5
#define MAXDEG 96

typedef __attribute__((ext_vector_type(8))) short s16x8;   // 8 bf16 in 4 VGPRs
typedef __attribute__((ext_vector_type(4))) float f32x4;   // MFMA accumulator

__device__ inline ushort bf16rne(float x) {
    uint32_t u = __float_as_uint(x);
    u += 0x7fffu + ((u >> 16) & 1u);
    return (ushort)(u >> 16);
}
__device__ inline s16x8 cvt8(float4 a, float4 b) {
    s16x8 v;
    v[0] = (short)bf16rne(a.x); v[1] = (short)bf16rne(a.y);
    v[2] = (short)bf16rne(a.z); v[3] = (short)bf16rne(a.w);
    v[4] = (short)bf16rne(b.x); v[5] = (short)bf16rne(b.y);
    v[6] = (short)bf16rne(b.z); v[7] = (short)bf16rne(b.w);
    return v;
}

// ---------------------------------------------------------------------------
// init: copy node_feats into both output halves (td at 0, bu at NV*512)
__global__ void init_copy(const float* __restrict__ nf, float* __restrict__ out) {
    int i = blockIdx.x * 256 + threadIdx.x;              // exactly NV*512/4 threads
    float4 v = reinterpret_cast<const float4*>(nf)[i];
    reinterpret_cast<float4*>(out)[i] = v;
    reinterpret_cast<float4*>(out + (size_t)NV * 512)[i] = v;
}

// ---------------------------------------------------------------------------
// fold: build 3 bf16 [16][512] matrices (transposed fold, MFMA-B-ready):
//  arr0 = Wn_bu fold (rows 0-7 aw_j, 8-15 aw_i)
//  arr1 = Wn_td fold
//  arr2 = We fold (rows 0-7 bu edge-alpha, 8-15 td)
__global__ void fold_kernel(
    const float* __restrict__ Wn_bu, const float* __restrict__ attn_bu,
    const float* __restrict__ Wn_td, const float* __restrict__ attn_td,
    const float* __restrict__ We_bu, const float* __restrict__ We_td,
    ushort* __restrict__ foldT)
{
    int idx = blockIdx.x * 256 + threadIdx.x;
    if (idx >= 3 * 8192) return;
    int arr = idx >> 13;
    int r = idx & 8191;
    int d = r >> 4;
    int o = r & 15;
    int h = o & 7;
    const float* W; const float* attn; int awOff;
    if (arr == 0)      { W = Wn_bu; attn = attn_bu; awOff = (o < 8) ? 0 : 64; }
    else if (arr == 1) { W = Wn_td; attn = attn_td; awOff = (o < 8) ? 0 : 64; }
    else               { W = (o < 8) ? We_bu : We_td; attn = (o < 8) ? attn_bu : attn_td; awOff = 128; }
    float s = 0.f;
    for (int cc = 0; cc < 64; ++cc)
        s += W[d * 512 + h * 64 + cc] * attn[h * 192 + awOff + cc];
    foldT[arr * 8192 + o * 512 + d] = bf16rne(s);
}

// ---------------------------------------------------------------------------
// prep_w: transpose+convert 4 [512][512] fp32 weights to bf16 Bt[n][k].
// 256 blocks (4 mats x 8x8 tiles of 64x64), 256 threads.
__global__ __launch_bounds__(256) void prep_w(
    const float* __restrict__ W0, const float* __restrict__ W1,
    const float* __restrict__ W2, const float* __restrict__ W3,
    ushort* __restrict__ Bt)
{
    __shared__ float T[64][65];
    const int t = threadIdx.x;
    const int b = blockIdx.x;
    const int mat = b >> 6;
    const int tk = (b >> 3) & 7, tn = b & 7;
    const float* W = (mat == 0) ? W0 : (mat == 1) ? W1 : (mat == 2) ? W2 : W3;
    const int k0 = tk * 64, n0 = tn * 64;
    #pragma unroll
    for (int i = 0; i < 4; ++i) {
        int r = (t >> 4) * 4 + i;
        int c = (t & 15) * 4;
        float4 v = *reinterpret_cast<const float4*>(W + (size_t)(k0 + r) * 512 + n0 + c);
        T[r][c + 0] = v.x; T[r][c + 1] = v.y; T[r][c + 2] = v.z; T[r][c + 3] = v.w;
    }
    __syncthreads();
    #pragma unroll
    for (int i = 0; i < 4; ++i) {
        int n = (t >> 4) * 4 + i;
        int c = (t & 15) * 4;
        ushort4 o;
        o.x = bf16rne(T[c + 0][n]); o.y = bf16rne(T[c + 1][n]);
        o.z = bf16rne(T[c + 2][n]); o.w = bf16rne(T[c + 3][n]);
        *reinterpret_cast<ushort4*>(Bt + (size_t)mat * 262144 + (size_t)(n0 + n) * 512 + k0 + c) = o;
    }
}

// ---------------------------------------------------------------------------
// rowdot_mfma: out[r][0..16) = rows[r][0..512) @ BtT[o][...]  via MFMA N=16.
// One wave per 16-row tile; A loaded straight from global in fragment layout;
// Bt (bf16 [16][512]) staged once into LDS (padded row 520 -> conflict-free).
__global__ __launch_bounds__(256) void rowdot_mfma(
    const float* __restrict__ A, int nTiles,
    const ushort* __restrict__ Bt16, float* __restrict__ out)
{
    __shared__ ushort Bs[16][520];
    const int t = threadIdx.x;
    for (int i = t; i < 16 * 512; i += 256)
        Bs[i >> 9][i & 511] = Bt16[i];
    __syncthreads();
    const int wave = t >> 6, lane = t & 63;
    const int tile = blockIdx.x * 4 + wave;
    if (tile >= nTiles) return;
    const int fr = lane & 15;            // A row / B col
    const int fk = (lane >> 4) * 8;      // k-group base
    const float* Ar = A + (size_t)tile * 16 * 512 + (size_t)fr * 512;
    f32x4 acc = {0.f, 0.f, 0.f, 0.f};
    #pragma unroll
    for (int k0 = 0; k0 < 512; k0 += 32) {
        float4 a0 = *reinterpret_cast<const float4*>(Ar + k0 + fk);
        float4 a1 = *reinterpret_cast<const float4*>(Ar + k0 + fk + 4);
        s16x8 av = cvt8(a0, a1);
        s16x8 bv = *reinterpret_cast<const s16x8*>(&Bs[fr][k0 + fk]);
        acc = __builtin_amdgcn_mfma_f32_16x16x32_bf16(av, bv, acc, 0, 0, 0);
    }
    #pragma unroll
    for (int i = 0; i < 4; ++i) {
        int r = tile * 16 + (lane >> 4) * 4 + i;
        out[(size_t)r * 16 + (lane & 15)] = acc[i];
    }
}

// ---------------------------------------------------------------------------
// gemm_mfma: C[M x 512] = A[M x 512 fp32] @ (Bt bf16, pre-transposed [n][k]) + bias
// 64x64 tile, 256 threads = 4 waves in 2x2, each wave 32x32 via 4 MFMAs/K-step.
__global__ __launch_bounds__(256) void gemm_mfma(
    const float* __restrict__ A, const ushort* __restrict__ Bt,
    float* __restrict__ C, int M, const float* __restrict__ bias)
{
    __shared__ ushort As[64][40];
    __shared__ ushort Bs[64][40];
    const int t = threadIdx.x;
    const int wave = t >> 6, lane = t & 63;
    const int row0 = blockIdx.x * 64, col0 = blockIdx.y * 64;
    const int wm = (wave >> 1) * 32, wn = (wave & 1) * 32;
    const int sm = t >> 2;              // staging row 0..63
    const int sk = (t & 3) * 8;         // staging k-offset
    const int fr = lane & 15;
    const int fk = (lane >> 4) * 8;
    const bool aok = (row0 + sm) < M;
    const float* Ap = A + (size_t)(row0 + sm) * 512;
    const ushort* Bp = Bt + (size_t)(col0 + sm) * 512;
    f32x4 acc[2][2];
    #pragma unroll
    for (int mi = 0; mi < 2; ++mi)
        #pragma unroll
        for (int ni = 0; ni < 2; ++ni) acc[mi][ni] = (f32x4){0.f, 0.f, 0.f, 0.f};

    for (int k0 = 0; k0 < 512; k0 += 32) {
        float4 a0, a1;
        if (aok) {
            a0 = *reinterpret_cast<const float4*>(Ap + k0 + sk);
            a1 = *reinterpret_cast<const float4*>(Ap + k0 + sk + 4);
        } else {
            a0 = make_float4(0.f, 0.f, 0.f, 0.f);
            a1 = a0;
        }
        *reinterpret_cast<s16x8*>(&As[sm][sk]) = cvt8(a0, a1);
        *reinterpret_cast<s16x8*>(&Bs[sm][sk]) =
            *reinterpret_cast<const s16x8*>(Bp + k0 + sk);
        __syncthreads();
        s16x8 af[2], bf[2];
        af[0] = *reinterpret_cast<const s16x8*>(&As[wm + fr][fk]);
        af[1] = *reinterpret_cast<const s16x8*>(&As[wm + 16 + fr][fk]);
        bf[0] = *reinterpret_cast<const s16x8*>(&Bs[wn + fr][fk]);
        bf[1] = *reinterpret_cast<const s16x8*>(&Bs[wn + 16 + fr][fk]);
        acc[0][0] = __builtin_amdgcn_mfma_f32_16x16x32_bf16(af[0], bf[0], acc[0][0], 0, 0, 0);
        acc[0][1] = __builtin_amdgcn_mfma_f32_16x16x32_bf16(af[0], bf[1], acc[0][1], 0, 0, 0);
        acc[1][0] = __builtin_amdgcn_mfma_f32_16x16x32_bf16(af[1], bf[0], acc[1][0], 0, 0, 0);
        acc[1][1] = __builtin_amdgcn_mfma_f32_16x16x32_bf16(af[1], bf[1], acc[1][1], 0, 0, 0);
        __syncthreads();
    }
    #pragma unroll
    for (int mi = 0; mi < 2; ++mi) {
        #pragma unroll
        for (int ni = 0; ni < 2; ++ni) {
            int c = col0 + wn + ni * 16 + (lane & 15);
            float bb = bias ? bias[c] : 0.f;
            #pragma unroll
            for (int i = 0; i < 4; ++i) {
                int r = row0 + wm + mi * 16 + (lane >> 4) * 4 + i;
                if (r < M) C[(size_t)r * 512 + c] = acc[mi][ni][i] + bb;
            }
        }
    }
}

// ---------------------------------------------------------------------------
// CSR build for the TD direction (3 level blocks of 80000 edges, 5000 targets each)
__global__ void csr_zero(int* cnt) {
    int i = blockIdx.x * 256 + threadIdx.x;
    if (i < 15000) cnt[i] = 0;
}
__global__ void csr_count(const int* __restrict__ ei, int* __restrict__ cnt) {
    int e = blockIdx.x * 256 + threadIdx.x;
    if (e >= NE) return;
    int lv = e / EPB;
    int local = ei[e] - lv * PER;   // orig src is the TD target; lives in level lv
    atomicAdd(&cnt[lv * PER + local], 1);
}
__global__ void csr_scan(const int* __restrict__ cnt, int* __restrict__ rptr) {
    __shared__ int part[256];
    int lv = blockIdx.x, t = threadIdx.x;
    int s = 0;
    if (t < 250)
        for (int j = 0; j < 20; ++j) s += cnt[lv * PER + t * 20 + j];
    part[t] = s;
    __syncthreads();
    if (t == 0) {
        int run = 0;
        for (int i = 0; i < 250; ++i) { int v = part[i]; part[i] = run; run += v; }
        rptr[lv * 5001 + 5000] = run;
    }
    __syncthreads();
    if (t < 250) {
        int run = part[t];
        for (int j = 0; j < 20; ++j) {
            int idx = t * 20 + j;
            rptr[lv * 5001 + idx] = run;
            run += cnt[lv * PER + idx];
        }
    }
}
__global__ void csr_offinit(const int* __restrict__ rptr, int* __restrict__ off) {
    int i = blockIdx.x * 256 + threadIdx.x;
    if (i >= 15000) return;
    int lv = i / PER, local = i - lv * PER;
    off[i] = rptr[lv * 5001 + local];
}
__global__ void csr_fill(const int* __restrict__ ei, int* __restrict__ off, int* __restrict__ eids) {
    int e = blockIdx.x * 256 + threadIdx.x;
    if (e >= NE) return;
    int lv = e / EPB;
    int local = ei[e] - lv * PER;
    int pos = atomicAdd(&off[lv * PER + local], 1);   // level-local position
    eids[lv * EPB + pos] = e;
}

// ---------------------------------------------------------------------------
// Attention + softmax + aggregation for one level. One block (512 thr) per target.
// xp/ajai are window-relative (window = [base, base+10000) global node rows).
template<bool FIXED>
__global__ __launch_bounds__(512) void attn_kernel(
    const float* __restrict__ xp,    // [10000][512]
    const float* __restrict__ ajai,  // [10000][16]  (0-7 aj, 8-15 ai)
    const float* __restrict__ epA,   // [NE][16]     (0-7 bu, 8-15 td)
    const int* __restrict__ srcArr,  // global edge -> src node id (this direction)
    const int* __restrict__ rptr,    // TD only (level-local)
    const int* __restrict__ eids,    // TD only (level-local -> global edge id)
    int eBase,                       // BU only: first edge of block
    int base,                        // window base (global node id)
    int tgtLocOff,                   // xp-local offset of targets (BU:5000, TD:0)
    int dirOff,                      // epA column offset (BU:0, TD:8)
    float* __restrict__ aggn)        // [5000][512]
{
    __shared__ float Lwe[MAXDEG][8];
    __shared__ int   Lsrci[MAXDEG];
    __shared__ float Lws[8];
    __shared__ float Ldenom[8];
    const int t = blockIdx.x;
    const int tid = threadIdx.x;
    const int tgtXp = tgtLocOff + t;

    int deg, ebase;
    if (FIXED) { deg = DEG; ebase = eBase + t * DEG; }
    else       { int r0 = rptr[t]; deg = rptr[t + 1] - r0; ebase = r0; }
    if (deg > MAXDEG) deg = MAXDEG;

    for (int kk = tid; kk < deg * 8; kk += 512) {
        int k = kk >> 3, h = kk & 7;
        int e = FIXED ? (ebase + k) : eids[ebase + k];
        int src = srcArr[e] - base;
        float lg = (ajai[src * 16 + h] + ajai[tgtXp * 16 + 8 + h] + epA[(size_t)e * 16 + dirOff + h]) * SCALE;
        Lwe[k][h] = lg;
        if (h == 0) Lsrci[k] = src;
    }
    if (tid < 8) Lws[tid] = (ajai[tgtXp * 16 + tid] + ajai[tgtXp * 16 + 8 + tid]) * SCALE;
    __syncthreads();
    if (tid < 8) {
        float m = Lws[tid];
        for (int k = 0; k < deg; ++k) m = fmaxf(m, Lwe[k][tid]);
        float dsum = 0.f;
        for (int k = 0; k < deg; ++k) {
            float w = expf(Lwe[k][tid] - m);
            Lwe[k][tid] = w;
            dsum += w;
        }
        float wsv = expf(Lws[tid] - m);
        Lws[tid] = wsv;
        Ldenom[tid] = dsum + wsv;
    }
    __syncthreads();
    const int h = tid >> 6, c = tid & 63;
    float acc = Lws[h] * xp[(size_t)tgtXp * 512 + h * 64 + c];
    if (FIXED) {
        #pragma unroll
        for (int k = 0; k < DEG; ++k)
            acc += Lwe[k][h] * xp[(size_t)Lsrci[k] * 512 + h * 64 + c];
    } else {
        #pragma unroll 4
        for (int k = 0; k < deg; ++k)
            acc += Lwe[k][h] * xp[(size_t)Lsrci[k] * 512 + h * 64 + c];
    }
    aggn[(size_t)t * 512 + h * 64 + c] = acc / Ldenom[h];
}

// ---------------------------------------------------------------------------
extern "C" void kernel_launch(void* const* d_in, const int* in_sizes, int n_in,
                              void* d_out, int out_size, void* d_ws, size_t ws_size,
                              hipStream_t stream) {
    const float* node_feats = (const float*)d_in[0];
    const float* edge_feats = (const float*)d_in[1];
    const int*   edge_index = (const int*)d_in[2];
    const float* Wn_bu  = (const float*)d_in[5];
    const float* We_bu  = (const float*)d_in[6];
    const float* attn_bu = (const float*)d_in[7];
    const float* Wo_bu  = (const float*)d_in[8];
    const float* bo_bu  = (const float*)d_in[9];
    const float* Wn_td  = (const float*)d_in[10];
    const float* We_td  = (const float*)d_in[11];
    const float* attn_td = (const float*)d_in[12];
    const float* Wo_td  = (const float*)d_in[13];
    const float* bo_td  = (const float*)d_in[14];

    float* out = (float*)d_out;
    float* td = out;
    float* bu = out + (size_t)NV * 512;

    float* ws   = (float*)d_ws;
    float* xp   = ws;                         // 10000*512    = 5,120,000
    float* aggn = xp + 5120000;               // 5000*512     = 2,560,000
    float* ajai = aggn + 2560000;             // 10000*16     = 160,000
    float* epA  = ajai + 160000;              // 240000*16    = 3,840,000
    int* cnt  = (int*)(epA + 3840000);        // 15,000
    int* off  = cnt + 15000;                  // 15,000
    int* rptr = off + 15000;                  // 3*5001 -> pad 15,008
    int* eids = rptr + 15008;                 // 240,000
    ushort* BtW   = (ushort*)(eids + 240000); // 4*262144 bf16 (Wn_bu,Wo_bu,Wn_td,Wo_td transposed)
    ushort* foldT = BtW + 4 * 262144;         // 3*8192 bf16

    const int* ei_src = edge_index;           // orig src
    const int* ei_tgt = edge_index + NE;      // orig tgt

    init_copy<<<10000, 256, 0, stream>>>(node_feats, out);
    fold_kernel<<<96, 256, 0, stream>>>(Wn_bu, attn_bu, Wn_td, attn_td, We_bu, We_td, foldT);
    prep_w<<<256, 256, 0, stream>>>(Wn_bu, Wo_bu, Wn_td, Wo_td, BtW);
    rowdot_mfma<<<3750, 256, 0, stream>>>(edge_feats, 15000, foldT + 2 * 8192, epA);

    csr_zero<<<59, 256, 0, stream>>>(cnt);
    csr_count<<<938, 256, 0, stream>>>(ei_src, cnt);
    csr_scan<<<3, 256, 0, stream>>>(cnt, rptr);
    csr_offinit<<<59, 256, 0, stream>>>(rptr, off);
    csr_fill<<<938, 256, 0, stream>>>(ei_src, off, eids);

    // Bottom-up: level l updates nodes [l*PER,(l+1)*PER) from level l-1
    for (int l = 1; l <= 3; ++l) {
        int base = (l - 1) * PER;
        gemm_mfma<<<dim3(157, 8), 256, 0, stream>>>(bu + (size_t)base * 512, BtW, xp, 10000, nullptr);
        rowdot_mfma<<<157, 256, 0, stream>>>(bu + (size_t)base * 512, 625, foldT, ajai);
        attn_kernel<true><<<5000, 512, 0, stream>>>(xp, ajai, epA, ei_src,
                                                    nullptr, nullptr, (l - 1) * EPB,
                                                    base, PER, 0, aggn);
        gemm_mfma<<<dim3(79, 8), 256, 0, stream>>>(aggn, BtW + 262144, bu + (size_t)(l * PER) * 512, 5000, bo_bu);
    }
    // Top-down: iter ltd updates orig level (3-ltd) from orig level (4-ltd), via reversed block 4-ltd
    for (int ltd = 1; ltd <= 3; ++ltd) {
        int lvIdx = 3 - ltd;                 // CSR block index
        int base = lvIdx * PER;
        gemm_mfma<<<dim3(157, 8), 256, 0, stream>>>(td + (size_t)base * 512, BtW + 2 * 262144, xp, 10000, nullptr);
        rowdot_mfma<<<157, 256, 0, stream>>>(td + (size_t)base * 512, 625, foldT + 8192, ajai);
        attn_kernel<false><<<5000, 512, 0, stream>>>(xp, ajai, epA, ei_tgt,
                                                     rptr + lvIdx * 5001, eids + lvIdx * EPB, 0,
                                                     base, 0, 8, aggn);
        gemm_mfma<<<dim3(79, 8), 256, 0, stream>>>(aggn, BtW + 3 * 262144, td + (size_t)base * 512, 5000, bo_td);
    }
}

// Round 4
// 1172.488 us; speedup vs baseline: 1.0643x; 1.0643x over previous
//
#include <hip/hip_runtime.h>

// Problem constants (fixed-shape problem)
#define NV 20000
#define NE 240000
#define PER 5000
#define DEG 16
#define EPB 80000            // edges per level block
#define SCALE 0.07216878364870323f   // (3*64)^-0.5
#define MAXDEG 96

typedef __attribute__((ext_vector_type(8))) short s16x8;   // 8 bf16 in 4 VGPRs
typedef __attribute__((ext_vector_type(4))) float f32x4;   // MFMA accumulator

__device__ inline ushort bf16rne(float x) {
    uint32_t u = __float_as_uint(x);
    u += 0x7fffu + ((u >> 16) & 1u);
    return (ushort)(u >> 16);
}
__device__ inline s16x8 cvt8(float4 a, float4 b) {
    s16x8 v;
    v[0] = (short)bf16rne(a.x); v[1] = (short)bf16rne(a.y);
    v[2] = (short)bf16rne(a.z); v[3] = (short)bf16rne(a.w);
    v[4] = (short)bf16rne(b.x); v[5] = (short)bf16rne(b.y);
    v[6] = (short)bf16rne(b.z); v[7] = (short)bf16rne(b.w);
    return v;
}

// ---------------------------------------------------------------------------
// init: copy node_feats into both output halves (td at 0, bu at NV*512)
__global__ void init_copy(const float* __restrict__ nf, float* __restrict__ out) {
    int i = blockIdx.x * 256 + threadIdx.x;              // exactly NV*512/4 threads
    float4 v = reinterpret_cast<const float4*>(nf)[i];
    reinterpret_cast<float4*>(out)[i] = v;
    reinterpret_cast<float4*>(out + (size_t)NV * 512)[i] = v;
}

// ---------------------------------------------------------------------------
// fold: build folded attention rows.
//  Bt1_bu rows 512..575 : rows 0-15 = Wn_bu fold (aj|ai), 16-63 zero pad
//  Bt1_td rows 512..575 : same for Wn_td
//  foldE [16][512]      : We fold (rows 0-7 bu edge-alpha, 8-15 td)
__global__ void fold_kernel(
    const float* __restrict__ Wn_bu, const float* __restrict__ attn_bu,
    const float* __restrict__ Wn_td, const float* __restrict__ attn_td,
    const float* __restrict__ We_bu, const float* __restrict__ We_td,
    ushort* __restrict__ Bt1_bu, ushort* __restrict__ Bt1_td,
    ushort* __restrict__ foldE)
{
    int idx = blockIdx.x * 256 + threadIdx.x;
    const int SZ = 64 * 512;
    if (idx < 2 * SZ) {
        int arr = idx / SZ;
        int r = idx - arr * SZ;
        int o = r >> 9;          // padded fold row 0..63
        int d = r & 511;         // k
        ushort val = 0;
        if (o < 16) {
            const float* W    = arr ? Wn_td   : Wn_bu;
            const float* attn = arr ? attn_td : attn_bu;
            int h = o & 7;
            int awOff = (o < 8) ? 0 : 64;
            float s = 0.f;
            for (int cc = 0; cc < 64; ++cc)
                s += W[d * 512 + h * 64 + cc] * attn[h * 192 + awOff + cc];
            val = bf16rne(s);
        }
        (arr ? Bt1_td : Bt1_bu)[(size_t)(512 + o) * 512 + d] = val;
    } else if (idx < 2 * SZ + 16 * 512) {
        int r = idx - 2 * SZ;
        int o = r >> 9;
        int d = r & 511;
        const float* W    = (o < 8) ? We_bu   : We_td;
        const float* attn = (o < 8) ? attn_bu : attn_td;
        int h = o & 7;
        float s = 0.f;
        for (int cc = 0; cc < 64; ++cc)
            s += W[d * 512 + h * 64 + cc] * attn[h * 192 + 128 + cc];
        foldE[o * 512 + d] = bf16rne(s);
    }
}

// ---------------------------------------------------------------------------
// prep_w: transpose+convert 4 [512][512] fp32 weights to bf16 Bt[n][k].
// 256 blocks (4 mats x 8x8 tiles of 64x64), 256 threads.
__global__ __launch_bounds__(256) void prep_w(
    const float* __restrict__ W0, const float* __restrict__ W1,
    const float* __restrict__ W2, const float* __restrict__ W3,
    ushort* __restrict__ Bt1_bu, ushort* __restrict__ Bt2_bu,
    ushort* __restrict__ Bt1_td, ushort* __restrict__ Bt2_td)
{
    __shared__ float T[64][65];
    const int t = threadIdx.x;
    const int b = blockIdx.x;
    const int mat = b >> 6;
    const int tk = (b >> 3) & 7, tn = b & 7;
    const float* W = (mat == 0) ? W0 : (mat == 1) ? W1 : (mat == 2) ? W2 : W3;
    ushort* outp = (mat == 0) ? Bt1_bu : (mat == 1) ? Bt2_bu : (mat == 2) ? Bt1_td : Bt2_td;
    const int k0 = tk * 64, n0 = tn * 64;
    #pragma unroll
    for (int i = 0; i < 4; ++i) {
        int r = (t >> 4) * 4 + i;
        int c = (t & 15) * 4;
        float4 v = *reinterpret_cast<const float4*>(W + (size_t)(k0 + r) * 512 + n0 + c);
        T[r][c + 0] = v.x; T[r][c + 1] = v.y; T[r][c + 2] = v.z; T[r][c + 3] = v.w;
    }
    __syncthreads();
    #pragma unroll
    for (int i = 0; i < 4; ++i) {
        int n = (t >> 4) * 4 + i;
        int c = (t & 15) * 4;
        ushort4 o;
        o.x = bf16rne(T[c + 0][n]); o.y = bf16rne(T[c + 1][n]);
        o.z = bf16rne(T[c + 2][n]); o.w = bf16rne(T[c + 3][n]);
        *reinterpret_cast<ushort4*>(outp + (size_t)(n0 + n) * 512 + k0 + c) = o;
    }
}

// ---------------------------------------------------------------------------
// rowdot_mfma: out[r][0..16) = rows[r][0..512) @ Bt16  via MFMA N=16.
// Used only for the edge-alpha precompute (240000 rows, HBM-bound).
__global__ __launch_bounds__(256) void rowdot_mfma(
    const float* __restrict__ A, int nTiles,
    const ushort* __restrict__ Bt16, float* __restrict__ out)
{
    __shared__ ushort Bs[16][520];
    const int t = threadIdx.x;
    for (int i = t; i < 16 * 512; i += 256)
        Bs[i >> 9][i & 511] = Bt16[i];
    __syncthreads();
    const int wave = t >> 6, lane = t & 63;
    const int tile = blockIdx.x * 4 + wave;
    if (tile >= nTiles) return;
    const int fr = lane & 15;            // A row / B col
    const int fk = (lane >> 4) * 8;      // k-group base
    const float* Ar = A + (size_t)tile * 16 * 512 + (size_t)fr * 512;
    f32x4 acc = {0.f, 0.f, 0.f, 0.f};
    #pragma unroll
    for (int k0 = 0; k0 < 512; k0 += 32) {
        float4 a0 = *reinterpret_cast<const float4*>(Ar + k0 + fk);
        float4 a1 = *reinterpret_cast<const float4*>(Ar + k0 + fk + 4);
        s16x8 av = cvt8(a0, a1);
        s16x8 bv = *reinterpret_cast<const s16x8*>(&Bs[fr][k0 + fk]);
        acc = __builtin_amdgcn_mfma_f32_16x16x32_bf16(av, bv, acc, 0, 0, 0);
    }
    #pragma unroll
    for (int i = 0; i < 4; ++i) {
        int r = tile * 16 + (lane >> 4) * 4 + i;
        out[(size_t)r * 16 + (lane & 15)] = acc[i];
    }
}

// ---------------------------------------------------------------------------
// gemm1_fused: for both directions (blockIdx.z): C[10000 x 576] = A @ Bt1
//   cols 0..511  -> xp ;  cols 512..527 -> ajai ;  cols 528..575 discarded
__global__ __launch_bounds__(256) void gemm1_fused(
    const float* __restrict__ Abu, const float* __restrict__ Atd,
    const ushort* __restrict__ Btbu, const ushort* __restrict__ Bttd,
    float* __restrict__ xpbu, float* __restrict__ xptd,
    float* __restrict__ ajbu, float* __restrict__ ajtd)
{
    __shared__ ushort As[64][40];
    __shared__ ushort Bs[64][40];
    const int z = blockIdx.z;
    const float* A   = z ? Atd  : Abu;
    const ushort* Bt = z ? Bttd : Btbu;
    float* xp = z ? xptd : xpbu;
    float* aj = z ? ajtd : ajbu;
    const int M = 10000;
    const int t = threadIdx.x;
    const int wave = t >> 6, lane = t & 63;
    const int row0 = blockIdx.x * 64, col0 = blockIdx.y * 64;
    const int wm = (wave >> 1) * 32, wn = (wave & 1) * 32;
    const int sm = t >> 2;
    const int sk = (t & 3) * 8;
    const int fr = lane & 15;
    const int fk = (lane >> 4) * 8;
    const bool aok = (row0 + sm) < M;
    const float* Ap = A + (size_t)(row0 + sm) * 512;
    const ushort* Bp = Bt + (size_t)(col0 + sm) * 512;
    f32x4 acc[2][2];
    #pragma unroll
    for (int mi = 0; mi < 2; ++mi)
        #pragma unroll
        for (int ni = 0; ni < 2; ++ni) acc[mi][ni] = (f32x4){0.f, 0.f, 0.f, 0.f};

    for (int k0 = 0; k0 < 512; k0 += 32) {
        float4 a0, a1;
        if (aok) {
            a0 = *reinterpret_cast<const float4*>(Ap + k0 + sk);
            a1 = *reinterpret_cast<const float4*>(Ap + k0 + sk + 4);
        } else {
            a0 = make_float4(0.f, 0.f, 0.f, 0.f);
            a1 = a0;
        }
        *reinterpret_cast<s16x8*>(&As[sm][sk]) = cvt8(a0, a1);
        *reinterpret_cast<s16x8*>(&Bs[sm][sk]) =
            *reinterpret_cast<const s16x8*>(Bp + k0 + sk);
        __syncthreads();
        s16x8 af[2], bf[2];
        af[0] = *reinterpret_cast<const s16x8*>(&As[wm + fr][fk]);
        af[1] = *reinterpret_cast<const s16x8*>(&As[wm + 16 + fr][fk]);
        bf[0] = *reinterpret_cast<const s16x8*>(&Bs[wn + fr][fk]);
        bf[1] = *reinterpret_cast<const s16x8*>(&Bs[wn + 16 + fr][fk]);
        acc[0][0] = __builtin_amdgcn_mfma_f32_16x16x32_bf16(af[0], bf[0], acc[0][0], 0, 0, 0);
        acc[0][1] = __builtin_amdgcn_mfma_f32_16x16x32_bf16(af[0], bf[1], acc[0][1], 0, 0, 0);
        acc[1][0] = __builtin_amdgcn_mfma_f32_16x16x32_bf16(af[1], bf[0], acc[1][0], 0, 0, 0);
        acc[1][1] = __builtin_amdgcn_mfma_f32_16x16x32_bf16(af[1], bf[1], acc[1][1], 0, 0, 0);
        __syncthreads();
    }
    #pragma unroll
    for (int mi = 0; mi < 2; ++mi) {
        #pragma unroll
        for (int ni = 0; ni < 2; ++ni) {
            int c = col0 + wn + ni * 16 + (lane & 15);
            #pragma unroll
            for (int i = 0; i < 4; ++i) {
                int r = row0 + wm + mi * 16 + (lane >> 4) * 4 + i;
                if (r < M) {
                    if (c < 512)       xp[(size_t)r * 512 + c] = acc[mi][ni][i];
                    else if (c < 528)  aj[(size_t)r * 16 + (c - 512)] = acc[mi][ni][i];
                }
            }
        }
    }
}

// ---------------------------------------------------------------------------
// gemm2_fused: both directions: C[5000 x 512] = aggn @ Wo^T + bias
__global__ __launch_bounds__(256) void gemm2_fused(
    const float* __restrict__ Abu, const float* __restrict__ Atd,
    const ushort* __restrict__ Btbu, const ushort* __restrict__ Bttd,
    float* __restrict__ Cbu, float* __restrict__ Ctd,
    const float* __restrict__ bbu, const float* __restrict__ btd)
{
    __shared__ ushort As[64][40];
    __shared__ ushort Bs[64][40];
    const int z = blockIdx.z;
    const float* A   = z ? Atd  : Abu;
    const ushort* Bt = z ? Bttd : Btbu;
    float* C = z ? Ctd : Cbu;
    const float* bias = z ? btd : bbu;
    const int M = 5000;
    const int t = threadIdx.x;
    const int wave = t >> 6, lane = t & 63;
    const int row0 = blockIdx.x * 64, col0 = blockIdx.y * 64;
    const int wm = (wave >> 1) * 32, wn = (wave & 1) * 32;
    const int sm = t >> 2;
    const int sk = (t & 3) * 8;
    const int fr = lane & 15;
    const int fk = (lane >> 4) * 8;
    const bool aok = (row0 + sm) < M;
    const float* Ap = A + (size_t)(row0 + sm) * 512;
    const ushort* Bp = Bt + (size_t)(col0 + sm) * 512;
    f32x4 acc[2][2];
    #pragma unroll
    for (int mi = 0; mi < 2; ++mi)
        #pragma unroll
        for (int ni = 0; ni < 2; ++ni) acc[mi][ni] = (f32x4){0.f, 0.f, 0.f, 0.f};

    for (int k0 = 0; k0 < 512; k0 += 32) {
        float4 a0, a1;
        if (aok) {
            a0 = *reinterpret_cast<const float4*>(Ap + k0 + sk);
            a1 = *reinterpret_cast<const float4*>(Ap + k0 + sk + 4);
        } else {
            a0 = make_float4(0.f, 0.f, 0.f, 0.f);
            a1 = a0;
        }
        *reinterpret_cast<s16x8*>(&As[sm][sk]) = cvt8(a0, a1);
        *reinterpret_cast<s16x8*>(&Bs[sm][sk]) =
            *reinterpret_cast<const s16x8*>(Bp + k0 + sk);
        __syncthreads();
        s16x8 af[2], bf[2];
        af[0] = *reinterpret_cast<const s16x8*>(&As[wm + fr][fk]);
        af[1] = *reinterpret_cast<const s16x8*>(&As[wm + 16 + fr][fk]);
        bf[0] = *reinterpret_cast<const s16x8*>(&Bs[wn + fr][fk]);
        bf[1] = *reinterpret_cast<const s16x8*>(&Bs[wn + 16 + fr][fk]);
        acc[0][0] = __builtin_amdgcn_mfma_f32_16x16x32_bf16(af[0], bf[0], acc[0][0], 0, 0, 0);
        acc[0][1] = __builtin_amdgcn_mfma_f32_16x16x32_bf16(af[0], bf[1], acc[0][1], 0, 0, 0);
        acc[1][0] = __builtin_amdgcn_mfma_f32_16x16x32_bf16(af[1], bf[0], acc[1][0], 0, 0, 0);
        acc[1][1] = __builtin_amdgcn_mfma_f32_16x16x32_bf16(af[1], bf[1], acc[1][1], 0, 0, 0);
        __syncthreads();
    }
    #pragma unroll
    for (int mi = 0; mi < 2; ++mi) {
        #pragma unroll
        for (int ni = 0; ni < 2; ++ni) {
            int c = col0 + wn + ni * 16 + (lane & 15);
            float bb = bias[c];
            #pragma unroll
            for (int i = 0; i < 4; ++i) {
                int r = row0 + wm + mi * 16 + (lane >> 4) * 4 + i;
                if (r < M) C[(size_t)r * 512 + c] = acc[mi][ni][i] + bb;
            }
        }
    }
}

// ---------------------------------------------------------------------------
// CSR build for the TD direction (3 level blocks of 80000 edges, 5000 targets each)
__global__ void csr_zero(int* cnt) {
    int i = blockIdx.x * 256 + threadIdx.x;
    if (i < 15000) cnt[i] = 0;
}
__global__ void csr_count(const int* __restrict__ ei, int* __restrict__ cnt) {
    int e = blockIdx.x * 256 + threadIdx.x;
    if (e >= NE) return;
    int lv = e / EPB;
    int local = ei[e] - lv * PER;   // orig src is the TD target; lives in level lv
    atomicAdd(&cnt[lv * PER + local], 1);
}
__global__ void csr_scan(const int* __restrict__ cnt, int* __restrict__ rptr,
                         int* __restrict__ off) {
    __shared__ int part[256];
    int lv = blockIdx.x, t = threadIdx.x;
    int s = 0;
    if (t < 250)
        for (int j = 0; j < 20; ++j) s += cnt[lv * PER + t * 20 + j];
    part[t] = s;
    __syncthreads();
    if (t == 0) {
        int run = 0;
        for (int i = 0; i < 250; ++i) { int v = part[i]; part[i] = run; run += v; }
        rptr[lv * 5001 + 5000] = run;
    }
    __syncthreads();
    if (t < 250) {
        int run = part[t];
        for (int j = 0; j < 20; ++j) {
            int idx = t * 20 + j;
            rptr[lv * 5001 + idx] = run;
            off[lv * PER + idx] = run;
            run += cnt[lv * PER + idx];
        }
    }
}
__global__ void csr_fill(const int* __restrict__ ei, int* __restrict__ off, int* __restrict__ eids) {
    int e = blockIdx.x * 256 + threadIdx.x;
    if (e >= NE) return;
    int lv = e / EPB;
    int local = ei[e] - lv * PER;
    int pos = atomicAdd(&off[lv * PER + local], 1);   // level-local position
    eids[lv * EPB + pos] = e;
}

// ---------------------------------------------------------------------------
// attn_fused: both directions in one launch.
// blocks [0,1250): BU (fixed deg 16); blocks [1250,2500): TD (CSR).
// 512 threads = 4 targets x 128 threads; float4 gather (16B/lane).
__global__ __launch_bounds__(512) void attn_fused(
    const float* __restrict__ xp_bu, const float* __restrict__ ajai_bu,
    const float* __restrict__ xp_td, const float* __restrict__ ajai_td,
    const float* __restrict__ epA,
    const int* __restrict__ ei_src, const int* __restrict__ ei_tgt,
    const int* __restrict__ rptr,    // TD slice (level-local)
    const int* __restrict__ eids,    // TD slice
    int eBaseBU, int baseBU, int baseTD,
    float* __restrict__ aggn_bu, float* __restrict__ aggn_td)
{
    __shared__ float Lwe[4][MAXDEG][8];
    __shared__ int   Lsrci[4][MAXDEG];
    __shared__ float Lws[4][8];
    __shared__ float Ldenom[4][8];
    const int tid = threadIdx.x;
    const int q = tid >> 7, f = tid & 127;
    const bool isBU = blockIdx.x < 1250;
    const int t = (isBU ? blockIdx.x : blockIdx.x - 1250) * 4 + q;

    const float* xp   = isBU ? xp_bu   : xp_td;
    const float* ajai = isBU ? ajai_bu : ajai_td;
    const int* srcArr = isBU ? ei_src  : ei_tgt;
    const int base    = isBU ? baseBU  : baseTD;
    const int tgtXp   = (isBU ? 5000 : 0) + t;
    const int dirOff  = isBU ? 0 : 8;
    float* aggn       = isBU ? aggn_bu : aggn_td;

    int deg, ebase;
    if (isBU) { deg = DEG; ebase = eBaseBU + t * DEG; }
    else      { int r0 = rptr[t]; deg = rptr[t + 1] - r0; ebase = r0; }
    if (deg > MAXDEG) deg = MAXDEG;

    const float tAi = ajai[tgtXp * 16 + 8 + (f & 7)];
    for (int kk = f; kk < deg * 8; kk += 128) {
        int k = kk >> 3, h = kk & 7;
        int e = isBU ? (ebase + k) : eids[ebase + k];
        int src = srcArr[e] - base;
        float lg = (ajai[src * 16 + h] + tAi + epA[(size_t)e * 16 + dirOff + h]) * SCALE;
        Lwe[q][k][h] = lg;
        if (h == 0) Lsrci[q][k] = src;
    }
    if (f < 8) Lws[q][f] = (ajai[tgtXp * 16 + f] + ajai[tgtXp * 16 + 8 + f]) * SCALE;
    __syncthreads();
    if (f < 8) {
        float m = Lws[q][f];
        for (int k = 0; k < deg; ++k) m = fmaxf(m, Lwe[q][k][f]);
        float dsum = 0.f;
        for (int k = 0; k < deg; ++k) {
            float w = expf(Lwe[q][k][f] - m);
            Lwe[q][k][f] = w;
            dsum += w;
        }
        float wsv = expf(Lws[q][f] - m);
        Lws[q][f] = wsv;
        Ldenom[q][f] = dsum + wsv;
    }
    __syncthreads();
    // aggregation: thread f covers cols 4f..4f+3; head h = f>>4 (4f>>6)
    const int h = f >> 4;
    const float4* xp4 = reinterpret_cast<const float4*>(xp);
    float4 xv = xp4[(size_t)tgtXp * 128 + f];
    float w0 = Lws[q][h];
    float ax = w0 * xv.x, ay = w0 * xv.y, az = w0 * xv.z, aw = w0 * xv.w;
    if (isBU) {
        #pragma unroll
        for (int k = 0; k < DEG; ++k) {
            float w = Lwe[q][k][h];
            float4 v = xp4[(size_t)Lsrci[q][k] * 128 + f];
            ax += w * v.x; ay += w * v.y; az += w * v.z; aw += w * v.w;
        }
    } else {
        #pragma unroll 4
        for (int k = 0; k < deg; ++k) {
            float w = Lwe[q][k][h];
            float4 v = xp4[(size_t)Lsrci[q][k] * 128 + f];
            ax += w * v.x; ay += w * v.y; az += w * v.z; aw += w * v.w;
        }
    }
    float inv = 1.f / Ldenom[q][h];
    float4 r; r.x = ax * inv; r.y = ay * inv; r.z = az * inv; r.w = aw * inv;
    reinterpret_cast<float4*>(aggn)[(size_t)t * 128 + f] = r;
}

// ---------------------------------------------------------------------------
extern "C" void kernel_launch(void* const* d_in, const int* in_sizes, int n_in,
                              void* d_out, int out_size, void* d_ws, size_t ws_size,
                              hipStream_t stream) {
    const float* node_feats = (const float*)d_in[0];
    const float* edge_feats = (const float*)d_in[1];
    const int*   edge_index = (const int*)d_in[2];
    const float* Wn_bu  = (const float*)d_in[5];
    const float* We_bu  = (const float*)d_in[6];
    const float* attn_bu = (const float*)d_in[7];
    const float* Wo_bu  = (const float*)d_in[8];
    const float* bo_bu  = (const float*)d_in[9];
    const float* Wn_td  = (const float*)d_in[10];
    const float* We_td  = (const float*)d_in[11];
    const float* attn_td = (const float*)d_in[12];
    const float* Wo_td  = (const float*)d_in[13];
    const float* bo_td  = (const float*)d_in[14];

    float* out = (float*)d_out;
    float* td = out;
    float* bu = out + (size_t)NV * 512;

    float* ws      = (float*)d_ws;
    float* xp_bu   = ws;                       // 5,120,000
    float* xp_td   = xp_bu + 5120000;          // 5,120,000
    float* aggn_bu = xp_td + 5120000;          // 2,560,000
    float* aggn_td = aggn_bu + 2560000;        // 2,560,000
    float* ajai_bu = aggn_td + 2560000;        // 160,000
    float* ajai_td = ajai_bu + 160000;         // 160,000
    float* epA     = ajai_td + 160000;         // 3,840,000
    int* cnt  = (int*)(epA + 3840000);         // 15,000
    int* off  = cnt + 15000;                   // 15,000
    int* rptr = off + 15000;                   // 3*5001 -> pad 15,008
    int* eids = rptr + 15008;                  // 240,000
    ushort* Bt1_bu = (ushort*)(eids + 240000); // 576*512
    ushort* Bt1_td = Bt1_bu + 294912;          // 576*512
    ushort* Bt2_bu = Bt1_td + 294912;          // 512*512
    ushort* Bt2_td = Bt2_bu + 262144;          // 512*512
    ushort* foldE  = Bt2_td + 262144;          // 16*512

    const int* ei_src = edge_index;            // orig src
    const int* ei_tgt = edge_index + NE;       // orig tgt

    init_copy<<<10000, 256, 0, stream>>>(node_feats, out);
    fold_kernel<<<288, 256, 0, stream>>>(Wn_bu, attn_bu, Wn_td, attn_td, We_bu, We_td,
                                         Bt1_bu, Bt1_td, foldE);
    prep_w<<<256, 256, 0, stream>>>(Wn_bu, Wo_bu, Wn_td, Wo_td,
                                    Bt1_bu, Bt2_bu, Bt1_td, Bt2_td);
    rowdot_mfma<<<3750, 256, 0, stream>>>(edge_feats, 15000, foldE, epA);

    csr_zero<<<59, 256, 0, stream>>>(cnt);
    csr_count<<<938, 256, 0, stream>>>(ei_src, cnt);
    csr_scan<<<3, 256, 0, stream>>>(cnt, rptr, off);
    csr_fill<<<938, 256, 0, stream>>>(ei_src, off, eids);

    // Paired steps: BU level l=i updates [i*PER,(i+1)*PER) from level i-1;
    //               TD iter updates orig level lvIdx=3-i from level lvIdx+1.
    for (int i = 1; i <= 3; ++i) {
        const int l = i, lvIdx = 3 - i;
        const int baseBU = (l - 1) * PER;
        const int baseTD = lvIdx * PER;
        gemm1_fused<<<dim3(157, 9, 2), 256, 0, stream>>>(
            bu + (size_t)baseBU * 512, td + (size_t)baseTD * 512,
            Bt1_bu, Bt1_td, xp_bu, xp_td, ajai_bu, ajai_td);
        attn_fused<<<2500, 512, 0, stream>>>(
            xp_bu, ajai_bu, xp_td, ajai_td, epA, ei_src, ei_tgt,
            rptr + lvIdx * 5001, eids + (size_t)lvIdx * EPB,
            (l - 1) * EPB, baseBU, baseTD, aggn_bu, aggn_td);
        gemm2_fused<<<dim3(79, 8, 2), 256, 0, stream>>>(
            aggn_bu, aggn_td, Bt2_bu, Bt2_td,
            bu + (size_t)l * PER * 512, td + (size_t)baseTD * 512,
            bo_bu, bo_td);
    }
}

// Round 5
// 1080.961 us; speedup vs baseline: 1.1545x; 1.0847x over previous
//
#include <hip/hip_runtime.h>

// Problem constants (fixed-shape problem)
#define NV 20000
#define NE 240000
#define PER 5000
#define DEG 16
#define EPB 80000            // edges per level block
#define SCALE 0.07216878364870323f   // (3*64)^-0.5
#define MAXDEG 96

typedef __attribute__((ext_vector_type(8))) short s16x8;   // 8 bf16 in 4 VGPRs
typedef __attribute__((ext_vector_type(4))) float f32x4;   // MFMA accumulator

__device__ inline ushort bf16rne(float x) {
    uint32_t u = __float_as_uint(x);
    u += 0x7fffu + ((u >> 16) & 1u);
    return (ushort)(u >> 16);
}

// ---------------------------------------------------------------------------
// init: copy node_feats into both output halves and both bf16 mirrors
__global__ void init_copy(const float* __restrict__ nf, float* __restrict__ out,
                          ushort* __restrict__ mbu, ushort* __restrict__ mtd) {
    int i = blockIdx.x * 256 + threadIdx.x;              // NV*512/4 threads
    float4 v = reinterpret_cast<const float4*>(nf)[i];
    reinterpret_cast<float4*>(out)[i] = v;
    reinterpret_cast<float4*>(out + (size_t)NV * 512)[i] = v;
    ushort4 m;
    m.x = bf16rne(v.x); m.y = bf16rne(v.y); m.z = bf16rne(v.z); m.w = bf16rne(v.w);
    reinterpret_cast<ushort4*>(mbu)[i] = m;
    reinterpret_cast<ushort4*>(mtd)[i] = m;
}

// ---------------------------------------------------------------------------
// fold: Bt1_* rows 512..639 (0-15 = Wn fold aj|ai, rest zero pad);
//       foldE [16][512] = We fold (rows 0-7 bu, 8-15 td)
__global__ void fold_kernel(
    const float* __restrict__ Wn_bu, const float* __restrict__ attn_bu,
    const float* __restrict__ Wn_td, const float* __restrict__ attn_td,
    const float* __restrict__ We_bu, const float* __restrict__ We_td,
    ushort* __restrict__ Bt1_bu, ushort* __restrict__ Bt1_td,
    ushort* __restrict__ foldE)
{
    int idx = blockIdx.x * 256 + threadIdx.x;
    const int SZ = 128 * 512;
    if (idx < 2 * SZ) {
        int arr = idx / SZ;
        int r = idx - arr * SZ;
        int o = r >> 9;          // padded fold row 0..127
        int d = r & 511;         // k
        ushort val = 0;
        if (o < 16) {
            const float* W    = arr ? Wn_td   : Wn_bu;
            const float* attn = arr ? attn_td : attn_bu;
            int h = o & 7;
            int awOff = (o < 8) ? 0 : 64;
            float s = 0.f;
            for (int cc = 0; cc < 64; ++cc)
                s += W[d * 512 + h * 64 + cc] * attn[h * 192 + awOff + cc];
            val = bf16rne(s);
        }
        (arr ? Bt1_td : Bt1_bu)[(size_t)(512 + o) * 512 + d] = val;
    } else if (idx < 2 * SZ + 16 * 512) {
        int r = idx - 2 * SZ;
        int o = r >> 9;
        int d = r & 511;
        const float* W    = (o < 8) ? We_bu   : We_td;
        const float* attn = (o < 8) ? attn_bu : attn_td;
        int h = o & 7;
        float s = 0.f;
        for (int cc = 0; cc < 64; ++cc)
            s += W[d * 512 + h * 64 + cc] * attn[h * 192 + 128 + cc];
        foldE[o * 512 + d] = bf16rne(s);
    }
}

// ---------------------------------------------------------------------------
// prep_w: transpose+convert 4 [512][512] fp32 weights to bf16 Bt[n][k].
__global__ __launch_bounds__(256) void prep_w(
    const float* __restrict__ W0, const float* __restrict__ W1,
    const float* __restrict__ W2, const float* __restrict__ W3,
    ushort* __restrict__ Bt1_bu, ushort* __restrict__ Bt2_bu,
    ushort* __restrict__ Bt1_td, ushort* __restrict__ Bt2_td)
{
    __shared__ float T[64][65];
    const int t = threadIdx.x;
    const int b = blockIdx.x;
    const int mat = b >> 6;
    const int tk = (b >> 3) & 7, tn = b & 7;
    const float* W = (mat == 0) ? W0 : (mat == 1) ? W1 : (mat == 2) ? W2 : W3;
    ushort* outp = (mat == 0) ? Bt1_bu : (mat == 1) ? Bt2_bu : (mat == 2) ? Bt1_td : Bt2_td;
    const int k0 = tk * 64, n0 = tn * 64;
    #pragma unroll
    for (int i = 0; i < 4; ++i) {
        int r = (t >> 4) * 4 + i;
        int c = (t & 15) * 4;
        float4 v = *reinterpret_cast<const float4*>(W + (size_t)(k0 + r) * 512 + n0 + c);
        T[r][c + 0] = v.x; T[r][c + 1] = v.y; T[r][c + 2] = v.z; T[r][c + 3] = v.w;
    }
    __syncthreads();
    #pragma unroll
    for (int i = 0; i < 4; ++i) {
        int n = (t >> 4) * 4 + i;
        int c = (t & 15) * 4;
        ushort4 o;
        o.x = bf16rne(T[c + 0][n]); o.y = bf16rne(T[c + 1][n]);
        o.z = bf16rne(T[c + 2][n]); o.w = bf16rne(T[c + 3][n]);
        *reinterpret_cast<ushort4*>(outp + (size_t)(n0 + n) * 512 + k0 + c) = o;
    }
}

// ---------------------------------------------------------------------------
// rowdot_mfma: epA precompute (240000 edge rows @ foldE) — HBM-bound one-shot.
__global__ __launch_bounds__(256) void rowdot_mfma(
    const float* __restrict__ A, int nTiles,
    const ushort* __restrict__ Bt16, float* __restrict__ out)
{
    __shared__ ushort Bs[16][520];
    const int t = threadIdx.x;
    for (int i = t; i < 16 * 512; i += 256)
        Bs[i >> 9][i & 511] = Bt16[i];
    __syncthreads();
    const int wave = t >> 6, lane = t & 63;
    const int tile = blockIdx.x * 4 + wave;
    if (tile >= nTiles) return;
    const int fr = lane & 15;
    const int fk = (lane >> 4) * 8;
    const float* Ar = A + (size_t)tile * 16 * 512 + (size_t)fr * 512;
    f32x4 acc = {0.f, 0.f, 0.f, 0.f};
    #pragma unroll
    for (int k0 = 0; k0 < 512; k0 += 32) {
        float4 a0 = *reinterpret_cast<const float4*>(Ar + k0 + fk);
        float4 a1 = *reinterpret_cast<const float4*>(Ar + k0 + fk + 4);
        s16x8 av;
        av[0] = (short)bf16rne(a0.x); av[1] = (short)bf16rne(a0.y);
        av[2] = (short)bf16rne(a0.z); av[3] = (short)bf16rne(a0.w);
        av[4] = (short)bf16rne(a1.x); av[5] = (short)bf16rne(a1.y);
        av[6] = (short)bf16rne(a1.z); av[7] = (short)bf16rne(a1.w);
        s16x8 bv = *reinterpret_cast<const s16x8*>(&Bs[fr][k0 + fk]);
        acc = __builtin_amdgcn_mfma_f32_16x16x32_bf16(av, bv, acc, 0, 0, 0);
    }
    #pragma unroll
    for (int i = 0; i < 4; ++i) {
        int r = tile * 16 + (lane >> 4) * 4 + i;
        out[(size_t)r * 16 + (lane & 15)] = acc[i];
    }
}

// ---------------------------------------------------------------------------
// gemm128: C[M x N] = A(bf16 [M][512]) @ Bt(bf16 [N][512], pre-transposed)
// 128x128 tile, 256 thr = 4 waves (2x2), each wave 64x64 via 4x4 MFMA frags.
// BK=64; reg-staged LDS with XOR swizzle slot^(row&7) on 16B granules
// (write side swizzled, read side same XOR -> 2-way max, free).
// MODE 0: outputs cols 0..511 -> xp (fp32), 512..527 -> ajai, rest dropped.
// MODE 1: C = acc + bias -> fp32 C and bf16 mirror.
template<int MODE>
__global__ __launch_bounds__(256) void gemm128(
    const ushort* __restrict__ Abu, const ushort* __restrict__ Atd,
    const ushort* __restrict__ Btbu, const ushort* __restrict__ Bttd,
    int M,
    float* __restrict__ f0bu, float* __restrict__ f0td,   // xp (0) or C (1)
    float* __restrict__ f1bu, float* __restrict__ f1td,   // ajai (0)
    ushort* __restrict__ mbu, ushort* __restrict__ mtd,   // mirror (1)
    const float* __restrict__ bbu, const float* __restrict__ btd)
{
    __shared__ ushort As[128 * 64];
    __shared__ ushort Bs[128 * 64];
    const int z = blockIdx.z;
    const ushort* A  = z ? Atd  : Abu;
    const ushort* Bt = z ? Bttd : Btbu;
    const int t = threadIdx.x;
    const int wave = t >> 6, lane = t & 63;
    const int row0 = blockIdx.x * 128, col0 = blockIdx.y * 128;
    const int wm = (wave >> 1) * 64, wn = (wave & 1) * 64;
    const int fr = lane & 15;
    const int fkg = lane >> 4;          // 0..3 -> k granule within 32-k slice

    f32x4 acc[4][4];
    #pragma unroll
    for (int mi = 0; mi < 4; ++mi)
        #pragma unroll
        for (int ni = 0; ni < 4; ++ni) acc[mi][ni] = (f32x4){0.f, 0.f, 0.f, 0.f};

    for (int k0 = 0; k0 < 512; k0 += 64) {
        s16x8 ra[4], rb[4];
        #pragma unroll
        for (int j = 0; j < 4; ++j) {
            int g = t + 256 * j;            // granule 0..1023
            int r = g >> 3, sl = g & 7;     // row 0..127, 16B slot 0..7
            ra[j] = *reinterpret_cast<const s16x8*>(A  + (size_t)(row0 + r) * 512 + k0 + sl * 8);
            rb[j] = *reinterpret_cast<const s16x8*>(Bt + (size_t)(col0 + r) * 512 + k0 + sl * 8);
        }
        __syncthreads();                    // prev compute done, LDS free
        #pragma unroll
        for (int j = 0; j < 4; ++j) {
            int g = t + 256 * j;
            int r = g >> 3, sl = g & 7;
            int so = (sl ^ (r & 7)) * 8;    // swizzled ushort offset in row
            *reinterpret_cast<s16x8*>(&As[r * 64 + so]) = ra[j];
            *reinterpret_cast<s16x8*>(&Bs[r * 64 + so]) = rb[j];
        }
        __syncthreads();                    // tile staged
        #pragma unroll
        for (int ks = 0; ks < 2; ++ks) {
            s16x8 av[4], bv[4];
            #pragma unroll
            for (int mi = 0; mi < 4; ++mi) {
                int row = wm + mi * 16 + fr;
                int cg = ks * 4 + fkg;      // col granule 0..7
                av[mi] = *reinterpret_cast<const s16x8*>(&As[row * 64 + ((cg ^ (row & 7)) * 8)]);
            }
            #pragma unroll
            for (int ni = 0; ni < 4; ++ni) {
                int row = wn + ni * 16 + fr;
                int cg = ks * 4 + fkg;
                bv[ni] = *reinterpret_cast<const s16x8*>(&Bs[row * 64 + ((cg ^ (row & 7)) * 8)]);
            }
            #pragma unroll
            for (int mi = 0; mi < 4; ++mi)
                #pragma unroll
                for (int ni = 0; ni < 4; ++ni)
                    acc[mi][ni] = __builtin_amdgcn_mfma_f32_16x16x32_bf16(av[mi], bv[ni], acc[mi][ni], 0, 0, 0);
        }
        __syncthreads();                    // compute done before restage
    }

    if (MODE == 0) {
        float* xp = z ? f0td : f0bu;
        float* aj = z ? f1td : f1bu;
        #pragma unroll
        for (int mi = 0; mi < 4; ++mi) {
            #pragma unroll
            for (int ni = 0; ni < 4; ++ni) {
                int c = col0 + wn + ni * 16 + (lane & 15);
                #pragma unroll
                for (int i = 0; i < 4; ++i) {
                    int r = row0 + wm + mi * 16 + (lane >> 4) * 4 + i;
                    if (r < M) {
                        float v = acc[mi][ni][i];
                        if (c < 512)      xp[(size_t)r * 512 + c] = v;
                        else if (c < 528) aj[(size_t)r * 16 + (c - 512)] = v;
                    }
                }
            }
        }
    } else {
        float* C = z ? f0td : f0bu;
        ushort* mir = z ? mtd : mbu;
        const float* bias = z ? btd : bbu;
        #pragma unroll
        for (int mi = 0; mi < 4; ++mi) {
            #pragma unroll
            for (int ni = 0; ni < 4; ++ni) {
                int c = col0 + wn + ni * 16 + (lane & 15);
                float bb = bias[c];
                #pragma unroll
                for (int i = 0; i < 4; ++i) {
                    int r = row0 + wm + mi * 16 + (lane >> 4) * 4 + i;
                    if (r < M) {
                        float v = acc[mi][ni][i] + bb;
                        C[(size_t)r * 512 + c] = v;
                        mir[(size_t)r * 512 + c] = bf16rne(v);
                    }
                }
            }
        }
    }
}

// ---------------------------------------------------------------------------
// CSR build for the TD direction
__global__ void csr_zero(int* cnt) {
    int i = blockIdx.x * 256 + threadIdx.x;
    if (i < 15000) cnt[i] = 0;
}
__global__ void csr_count(const int* __restrict__ ei, int* __restrict__ cnt) {
    int e = blockIdx.x * 256 + threadIdx.x;
    if (e >= NE) return;
    int lv = e / EPB;
    int local = ei[e] - lv * PER;
    atomicAdd(&cnt[lv * PER + local], 1);
}
__global__ void csr_scan(const int* __restrict__ cnt, int* __restrict__ rptr,
                         int* __restrict__ off) {
    __shared__ int part[256];
    int lv = blockIdx.x, t = threadIdx.x;
    int s = 0;
    if (t < 250)
        for (int j = 0; j < 20; ++j) s += cnt[lv * PER + t * 20 + j];
    part[t] = s;
    __syncthreads();
    if (t == 0) {
        int run = 0;
        for (int i = 0; i < 250; ++i) { int v = part[i]; part[i] = run; run += v; }
        rptr[lv * 5001 + 5000] = run;
    }
    __syncthreads();
    if (t < 250) {
        int run = part[t];
        for (int j = 0; j < 20; ++j) {
            int idx = t * 20 + j;
            rptr[lv * 5001 + idx] = run;
            off[lv * PER + idx] = run;
            run += cnt[lv * PER + idx];
        }
    }
}
__global__ void csr_fill(const int* __restrict__ ei, int* __restrict__ off, int* __restrict__ eids) {
    int e = blockIdx.x * 256 + threadIdx.x;
    if (e >= NE) return;
    int lv = e / EPB;
    int local = ei[e] - lv * PER;
    int pos = atomicAdd(&off[lv * PER + local], 1);
    eids[lv * EPB + pos] = e;
}

// ---------------------------------------------------------------------------
// attn_fused: both directions in one launch.
// blocks [0,1250): BU (fixed deg 16); [1250,2500): TD (CSR).
// 512 thr = 4 targets x 128 thr. Wave-parallel softmax (16 lanes/head via
// shfl_xor width 16); denom kept in registers; aggn written as bf16.
__global__ __launch_bounds__(512) void attn_fused(
    const float* __restrict__ xp_bu, const float* __restrict__ ajai_bu,
    const float* __restrict__ xp_td, const float* __restrict__ ajai_td,
    const float* __restrict__ epA,
    const int* __restrict__ ei_src, const int* __restrict__ ei_tgt,
    const int* __restrict__ rptr,
    const int* __restrict__ eids,
    int eBaseBU, int baseBU, int baseTD,
    ushort* __restrict__ aggn_bu, ushort* __restrict__ aggn_td)
{
    __shared__ float Lwe[4][MAXDEG][8];
    __shared__ int   Lsrci[4][MAXDEG];
    const int tid = threadIdx.x;
    const int q = tid >> 7, f = tid & 127;
    const bool isBU = blockIdx.x < 1250;
    const int t = (isBU ? blockIdx.x : blockIdx.x - 1250) * 4 + q;

    const float* xp   = isBU ? xp_bu   : xp_td;
    const float* ajai = isBU ? ajai_bu : ajai_td;
    const int* srcArr = isBU ? ei_src  : ei_tgt;
    const int base    = isBU ? baseBU  : baseTD;
    const int tgtXp   = (isBU ? 5000 : 0) + t;
    const int dirOff  = isBU ? 0 : 8;
    ushort* aggn      = isBU ? aggn_bu : aggn_td;

    int deg, ebase;
    if (isBU) { deg = DEG; ebase = eBaseBU + t * DEG; }
    else      { int r0 = rptr[t]; deg = rptr[t + 1] - r0; ebase = r0; }
    if (deg > MAXDEG) deg = MAXDEG;

    // phase 1: logits into LDS
    const float tAi = ajai[tgtXp * 16 + 8 + (f & 7)];
    for (int kk = f; kk < deg * 8; kk += 128) {
        int k = kk >> 3, h = kk & 7;
        int e = isBU ? (ebase + k) : eids[ebase + k];
        int src = srcArr[e] - base;
        float lg = (ajai[src * 16 + h] + tAi + epA[(size_t)e * 16 + dirOff + h]) * SCALE;
        Lwe[q][k][h] = lg;
        if (h == 0) Lsrci[q][k] = src;
    }
    __syncthreads();

    // phase 2: wave-parallel softmax. f = h*16 + s (h = f>>4 matches agg layout)
    const int h = f >> 4, s = f & 15;
    float sa = (ajai[tgtXp * 16 + h] + ajai[tgtXp * 16 + 8 + h]) * SCALE;
    float m = sa;
    for (int k = s; k < deg; k += 16) m = fmaxf(m, Lwe[q][k][h]);
    #pragma unroll
    for (int mk = 1; mk < 16; mk <<= 1) m = fmaxf(m, __shfl_xor(m, mk, 16));
    float dsum = 0.f;
    for (int k = s; k < deg; k += 16) {
        float w = expf(Lwe[q][k][h] - m);
        Lwe[q][k][h] = w;
        dsum += w;
    }
    #pragma unroll
    for (int mk = 1; mk < 16; mk <<= 1) dsum += __shfl_xor(dsum, mk, 16);
    const float wsv = expf(sa - m);
    const float inv = 1.f / (dsum + wsv);
    __syncthreads();

    // phase 3: aggregation; thread f covers cols 4f..4f+3 (head h = f>>4)
    const float4* xp4 = reinterpret_cast<const float4*>(xp);
    float4 xv = xp4[(size_t)tgtXp * 128 + f];
    float ax = wsv * xv.x, ay = wsv * xv.y, az = wsv * xv.z, aw = wsv * xv.w;
    if (isBU) {
        #pragma unroll
        for (int k = 0; k < DEG; ++k) {
            float w = Lwe[q][k][h];
            float4 v = xp4[(size_t)Lsrci[q][k] * 128 + f];
            ax += w * v.x; ay += w * v.y; az += w * v.z; aw += w * v.w;
        }
    } else {
        #pragma unroll 4
        for (int k = 0; k < deg; ++k) {
            float w = Lwe[q][k][h];
            float4 v = xp4[(size_t)Lsrci[q][k] * 128 + f];
            ax += w * v.x; ay += w * v.y; az += w * v.z; aw += w * v.w;
        }
    }
    ushort4 o;
    o.x = bf16rne(ax * inv); o.y = bf16rne(ay * inv);
    o.z = bf16rne(az * inv); o.w = bf16rne(aw * inv);
    *reinterpret_cast<ushort4*>(aggn + (size_t)t * 512 + f * 4) = o;
}

// ---------------------------------------------------------------------------
extern "C" void kernel_launch(void* const* d_in, const int* in_sizes, int n_in,
                              void* d_out, int out_size, void* d_ws, size_t ws_size,
                              hipStream_t stream) {
    const float* node_feats = (const float*)d_in[0];
    const float* edge_feats = (const float*)d_in[1];
    const int*   edge_index = (const int*)d_in[2];
    const float* Wn_bu  = (const float*)d_in[5];
    const float* We_bu  = (const float*)d_in[6];
    const float* attn_bu = (const float*)d_in[7];
    const float* Wo_bu  = (const float*)d_in[8];
    const float* bo_bu  = (const float*)d_in[9];
    const float* Wn_td  = (const float*)d_in[10];
    const float* We_td  = (const float*)d_in[11];
    const float* attn_td = (const float*)d_in[12];
    const float* Wo_td  = (const float*)d_in[13];
    const float* bo_td  = (const float*)d_in[14];

    float* out = (float*)d_out;
    float* td = out;
    float* bu = out + (size_t)NV * 512;

    float* ws      = (float*)d_ws;
    float* xp_bu   = ws;                       // 5,120,000
    float* xp_td   = xp_bu + 5120000;          // 5,120,000
    float* ajai_bu = xp_td + 5120000;          // 160,000
    float* ajai_td = ajai_bu + 160000;         // 160,000
    float* epA     = ajai_td + 160000;         // 3,840,000
    int* cnt  = (int*)(epA + 3840000);         // 15,000
    int* off  = cnt + 15000;                   // 15,000
    int* rptr = off + 15000;                   // 15,008 (3*5001 padded)
    int* eids = rptr + 15008;                  // 240,000
    ushort* aggn_bu = (ushort*)(eids + 240000);// 5120*512 bf16 (padded rows)
    ushort* aggn_td = aggn_bu + 2621440;       // 5120*512
    ushort* nf_bu   = aggn_td + 2621440;       // 20160*512 bf16 mirror (pad 160)
    ushort* nf_td   = nf_bu + 10321920;        // 20160*512
    ushort* Bt1_bu  = nf_td + 10321920;        // 640*512 (rows 512..639 fold/pad)
    ushort* Bt1_td  = Bt1_bu + 327680;         // 640*512
    ushort* Bt2_bu  = Bt1_td + 327680;         // 512*512
    ushort* Bt2_td  = Bt2_bu + 262144;         // 512*512
    ushort* foldE   = Bt2_td + 262144;         // 16*512

    const int* ei_src = edge_index;            // orig src
    const int* ei_tgt = edge_index + NE;       // orig tgt

    init_copy<<<10000, 256, 0, stream>>>(node_feats, out, nf_bu, nf_td);
    fold_kernel<<<544, 256, 0, stream>>>(Wn_bu, attn_bu, Wn_td, attn_td, We_bu, We_td,
                                         Bt1_bu, Bt1_td, foldE);
    prep_w<<<256, 256, 0, stream>>>(Wn_bu, Wo_bu, Wn_td, Wo_td,
                                    Bt1_bu, Bt2_bu, Bt1_td, Bt2_td);
    rowdot_mfma<<<3750, 256, 0, stream>>>(edge_feats, 15000, foldE, epA);

    csr_zero<<<59, 256, 0, stream>>>(cnt);
    csr_count<<<938, 256, 0, stream>>>(ei_src, cnt);
    csr_scan<<<3, 256, 0, stream>>>(cnt, rptr, off);
    csr_fill<<<938, 256, 0, stream>>>(ei_src, off, eids);

    // Paired steps: BU level l=i updates [i*PER,(i+1)*PER) from level i-1;
    //               TD iter updates orig level lvIdx=3-i from level lvIdx+1.
    for (int i = 1; i <= 3; ++i) {
        const int l = i, lvIdx = 3 - i;
        const int baseBU = (l - 1) * PER;
        const int baseTD = lvIdx * PER;
        gemm128<0><<<dim3(79, 5, 2), 256, 0, stream>>>(
            nf_bu + (size_t)baseBU * 512, nf_td + (size_t)baseTD * 512,
            Bt1_bu, Bt1_td, 10000,
            xp_bu, xp_td, ajai_bu, ajai_td,
            nullptr, nullptr, nullptr, nullptr);
        attn_fused<<<2500, 512, 0, stream>>>(
            xp_bu, ajai_bu, xp_td, ajai_td, epA, ei_src, ei_tgt,
            rptr + lvIdx * 5001, eids + (size_t)lvIdx * EPB,
            (l - 1) * EPB, baseBU, baseTD, aggn_bu, aggn_td);
        gemm128<1><<<dim3(40, 4, 2), 256, 0, stream>>>(
            aggn_bu, aggn_td, Bt2_bu, Bt2_td, 5000,
            bu + (size_t)l * PER * 512, td + (size_t)baseTD * 512,
            nullptr, nullptr,
            nf_bu + (size_t)l * PER * 512, nf_td + (size_t)baseTD * 512,
            bo_bu, bo_td);
    }
}